// Round 4
// baseline (1691.341 us; speedup 1.0000x reference)
//
#include <hip/hip_runtime.h>
#include <hip/hip_bf16.h>

// GAT-GAE forward: 2x GATConv + normalize + MLP decoder.
// Round 4: OUTPUT IS FP32 (reference returns float32; the harness doc maps
// output dtype from the reference — the "(bf16)" in the test label is only
// the threshold policy tag). Inputs confirmed fp32/int32 by the runtime
// detector (R3 bit-matched R2's fp32 path). Detector kept as insurance.
// Softmax max-shift skipped (shift-invariant, logits O(6), exp clamped @60).
//
// Workspace layout (fp32), zero-init region first:
//   out1[N*256] | denom1[N*4] | z0[N*64] | denom2[N] |  <-- memset 0
//   h1[N*256] | a_s1[N*4] | a_d1[N*4] | h2[N*64] | a_s2[N] | a_d2[N] | flags[16]

#define IN_DIM   128
#define C1       256   // HEADS*HID
#define HEADS    4
#define HID      64
#define OUT_DIM  64

__device__ __forceinline__ float lrelu(float x) { return x > 0.f ? x : 0.2f * x; }
__device__ __forceinline__ float elu1(float x)  { return x > 0.f ? x : (__expf(x) - 1.f); }
__device__ __forceinline__ float expc(float x)  { return __expf(fminf(x, 60.f)); }

// Flag-polymorphic load of float input i from buffer p (bf=1: bf16, bf=0: fp32).
__device__ __forceinline__ float ldf(const void* p, size_t i, int bf) {
    return bf ? __bfloat162float(((const __hip_bfloat16*)p)[i])
              : ((const float*)p)[i];
}
// Edge endpoint fetch; i64=1 means edge_index is int64.
__device__ __forceinline__ void edge_sd(const void* ei, int E, int e, int i64,
                                        int& s, int& d) {
    if (i64) { const long long* p = (const long long*)ei; s = (int)p[e]; d = (int)p[E + e]; }
    else     { const int*       p = (const int*)ei;       s = p[e];      d = p[E + e]; }
}

// ---------------- dtype detector ----------------
__global__ __launch_bounds__(256) void detect_k(const void* x, const void* ei,
                                                int* flags) {
    __shared__ int cnt_out, odd_nz, even_nz;
    if (threadIdx.x == 0) { cnt_out = 0; odd_nz = 0; even_nz = 0; }
    __syncthreads();
    const unsigned short* hx = (const unsigned short*)x;
    int c = 0;
    for (int i = threadIdx.x; i < 4096; i += 256) {
        const int ex = (hx[i] >> 7) & 0xFF;
        if (ex >= 140 || ex <= 60) ++c;
    }
    if (c) atomicAdd(&cnt_out, c);
    const int* w = (const int*)ei;
    int on = 0, en = 0;
    for (int i = threadIdx.x; i < 2048; i += 256) {
        if (w[i] != 0) { if (i & 1) on = 1; else en = 1; }
    }
    if (on) atomicOr(&odd_nz, 1);
    if (en) atomicOr(&even_nz, 1);
    __syncthreads();
    if (threadIdx.x == 0) {
        flags[0] = (cnt_out > 10) ? 0 : 1;        // 1 = float inputs are bf16
        flags[1] = (even_nz && !odd_nz) ? 1 : 0;  // 1 = edge_index is int64
    }
}

// ---------------- Layer 1: x @ W1 + attention logits ----------------
// block = 256 threads (4 waves = 4 heads), grid = N
__global__ __launch_bounds__(256) void gemm1_k(
    const void* __restrict__ x, const void* __restrict__ W1,
    const void* __restrict__ as1, const void* __restrict__ ad1,
    float* __restrict__ h1, float* __restrict__ a_s1, float* __restrict__ a_d1,
    const int* __restrict__ flags)
{
    const int bf = flags[0];
    __shared__ float xs[IN_DIM];
    const int n = blockIdx.x;
    const int t = threadIdx.x;
    if (t < IN_DIM) xs[t] = ldf(x, (size_t)n * IN_DIM + t, bf);
    __syncthreads();
    float acc = 0.f;
    #pragma unroll 8
    for (int k = 0; k < IN_DIM; ++k)
        acc += xs[k] * ldf(W1, (size_t)k * C1 + t, bf);
    h1[(size_t)n * C1 + t] = acc;
    float vs = acc * ldf(as1, t, bf);
    float vd = acc * ldf(ad1, t, bf);
    #pragma unroll
    for (int off = 32; off >= 1; off >>= 1) {
        vs += __shfl_down(vs, off, 64);
        vd += __shfl_down(vd, off, 64);
    }
    if ((t & 63) == 0) {
        const int head = t >> 6;
        a_s1[n * HEADS + head] = vs;
        a_d1[n * HEADS + head] = vd;
    }
}

// ---------------- denominator pass, layer 1 ----------------
__global__ void denom1_k(const void* __restrict__ ei, int E, int Etot,
                         const float* __restrict__ a_s1, const float* __restrict__ a_d1,
                         float* __restrict__ denom1, const int* __restrict__ flags)
{
    const int e = blockIdx.x * blockDim.x + threadIdx.x;
    if (e >= Etot) return;
    int s, d;
    if (e < E) edge_sd(ei, E, e, flags[1], s, d); else s = d = e - E;
    #pragma unroll
    for (int h = 0; h < HEADS; ++h) {
        const float w = expc(lrelu(a_s1[s * HEADS + h] + a_d1[d * HEADS + h]));
        atomicAdd(&denom1[d * HEADS + h], w);
    }
}

// ---------------- message scatter, layer 1 ----------------
__global__ __launch_bounds__(256) void scatter1_k(
    const void* __restrict__ ei, int E, int Etot,
    const float* __restrict__ a_s1, const float* __restrict__ a_d1,
    const float* __restrict__ denom1,
    const float* __restrict__ h1, float* __restrict__ out1,
    const int* __restrict__ flags)
{
    const int e = blockIdx.x;
    const int t = threadIdx.x;
    int s, d;
    if (e < E) edge_sd(ei, E, e, flags[1], s, d); else s = d = e - E;
    const int head = t >> 6;
    const float w = expc(lrelu(a_s1[s * HEADS + head] + a_d1[d * HEADS + head]));
    const float coeff = w / (denom1[d * HEADS + head] + 1e-16f);
    atomicAdd(&out1[(size_t)d * C1 + t], h1[(size_t)s * C1 + t] * coeff);
}

// ---------------- bias + ELU (in place: out1 -> h) ----------------
__global__ void bias_elu1_k(float* __restrict__ out1, const void* __restrict__ b1,
                            int total, const int* __restrict__ flags)
{
    const int i = blockIdx.x * blockDim.x + threadIdx.x;
    if (i >= total) return;
    out1[i] = elu1(out1[i] + ldf(b1, i & (C1 - 1), flags[0]));
}

// ---------------- Layer 2: h @ W2 + attention logits ----------------
// block = 64 threads (1 wave), grid = N
__global__ __launch_bounds__(64) void gemm2_k(
    const float* __restrict__ h, const void* __restrict__ W2,
    const void* __restrict__ as2, const void* __restrict__ ad2,
    float* __restrict__ h2, float* __restrict__ a_s2, float* __restrict__ a_d2,
    const int* __restrict__ flags)
{
    const int bf = flags[0];
    __shared__ float hs[C1];
    const int n = blockIdx.x;
    const int t = threadIdx.x;
    for (int i = t; i < C1; i += 64) hs[i] = h[(size_t)n * C1 + i];
    __syncthreads();
    float acc = 0.f;
    #pragma unroll 8
    for (int k = 0; k < C1; ++k)
        acc += hs[k] * ldf(W2, (size_t)k * OUT_DIM + t, bf);
    h2[(size_t)n * OUT_DIM + t] = acc;
    float vs = acc * ldf(as2, t, bf);
    float vd = acc * ldf(ad2, t, bf);
    #pragma unroll
    for (int off = 32; off >= 1; off >>= 1) {
        vs += __shfl_down(vs, off, 64);
        vd += __shfl_down(vd, off, 64);
    }
    if (t == 0) { a_s2[n] = vs; a_d2[n] = vd; }
}

// ---------------- denominator pass, layer 2 ----------------
__global__ void denom2_k(const void* __restrict__ ei, int E, int Etot,
                         const float* __restrict__ a_s2, const float* __restrict__ a_d2,
                         float* __restrict__ denom2, const int* __restrict__ flags)
{
    const int e = blockIdx.x * blockDim.x + threadIdx.x;
    if (e >= Etot) return;
    int s, d;
    if (e < E) edge_sd(ei, E, e, flags[1], s, d); else s = d = e - E;
    atomicAdd(&denom2[d], expc(lrelu(a_s2[s] + a_d2[d])));
}

// ---------------- message scatter, layer 2 ----------------
__global__ __launch_bounds__(64) void scatter2_k(
    const void* __restrict__ ei, int E, int Etot,
    const float* __restrict__ a_s2, const float* __restrict__ a_d2,
    const float* __restrict__ denom2,
    const float* __restrict__ h2, float* __restrict__ z0,
    const int* __restrict__ flags)
{
    const int e = blockIdx.x;
    const int t = threadIdx.x;
    int s, d;
    if (e < E) edge_sd(ei, E, e, flags[1], s, d); else s = d = e - E;
    const float w = expc(lrelu(a_s2[s] + a_d2[d]));
    const float coeff = w / (denom2[d] + 1e-16f);
    atomicAdd(&z0[(size_t)d * OUT_DIM + t], h2[(size_t)s * OUT_DIM + t] * coeff);
}

// ---------------- finalize: bias, L2-normalize, decoder, store (FP32) --------
// block = 64 (1 wave), grid = N
__global__ __launch_bounds__(64) void final_k(
    const float* __restrict__ z0, const void* __restrict__ b2,
    const void* __restrict__ dW1, const void* __restrict__ db1,
    const void* __restrict__ dW2, const void* __restrict__ db2,
    float* __restrict__ out, int N, const int* __restrict__ flags)
{
    const int bf = flags[0];
    __shared__ float zs[OUT_DIM];
    __shared__ float ts[HID];
    const int n = blockIdx.x;
    const int t = threadIdx.x;
    float zj = z0[(size_t)n * OUT_DIM + t] + ldf(b2, t, bf);
    float sq = zj * zj;
    #pragma unroll
    for (int off = 32; off >= 1; off >>= 1) sq += __shfl_xor(sq, off, 64);
    zj /= fmaxf(sqrtf(sq), 1e-12f);
    out[(size_t)n * OUT_DIM + t] = zj;
    zs[t] = zj;
    __syncthreads();
    float acc = ldf(db1, t, bf);
    #pragma unroll 8
    for (int k = 0; k < OUT_DIM; ++k)
        acc += zs[k] * ldf(dW1, k * HID + t, bf);
    ts[t] = elu1(acc);
    __syncthreads();
    #pragma unroll
    for (int rep = 0; rep < 2; ++rep) {
        const int i = t + rep * 64;
        float a2 = ldf(db2, i, bf);
        #pragma unroll 8
        for (int k = 0; k < HID; ++k)
            a2 += ts[k] * ldf(dW2, k * IN_DIM + i, bf);
        out[(size_t)N * OUT_DIM + (size_t)n * IN_DIM + i] = a2;
    }
}

extern "C" void kernel_launch(void* const* d_in, const int* in_sizes, int n_in,
                              void* d_out, int out_size, void* d_ws, size_t ws_size,
                              hipStream_t stream)
{
    const void* x   = d_in[0];
    const void* ei  = d_in[1];
    const void* W1  = d_in[2];
    const void* as1 = d_in[3];
    const void* ad1 = d_in[4];
    const void* b1  = d_in[5];
    const void* W2  = d_in[6];
    const void* as2 = d_in[7];
    const void* ad2 = d_in[8];
    const void* b2  = d_in[9];
    const void* dW1 = d_in[10];
    const void* db1 = d_in[11];
    const void* dW2 = d_in[12];
    const void* db2 = d_in[13];

    const int N    = in_sizes[0] / IN_DIM;
    const int E    = in_sizes[1] / 2;
    const int Etot = E + N;

    const size_t needed = (size_t)N * 655 * sizeof(float) + 64;
    if (ws_size < needed) return;  // signature: output stays 0 -> absmax ~0.543

    float* ws = (float*)d_ws;
    float* out1   = ws;                           // N*256  (zeroed; becomes h in place)
    float* denom1 = out1   + (size_t)N * C1;      // N*4    (zeroed)
    float* z0     = denom1 + (size_t)N * HEADS;   // N*64   (zeroed)
    float* denom2 = z0     + (size_t)N * OUT_DIM; // N      (zeroed)
    float* h1     = denom2 + (size_t)N;           // N*256
    float* a_s1   = h1     + (size_t)N * C1;      // N*4
    float* a_d1   = a_s1   + (size_t)N * HEADS;   // N*4
    float* h2     = a_d1   + (size_t)N * HEADS;   // N*64
    float* a_s2   = h2     + (size_t)N * OUT_DIM; // N
    float* a_d2   = a_s2   + (size_t)N;           // N
    int*   flags  = (int*)(a_d2 + (size_t)N);     // 16 ints

    const size_t zero_elems = (size_t)N * C1 + (size_t)N * HEADS
                            + (size_t)N * OUT_DIM + (size_t)N;
    hipMemsetAsync(out1, 0, zero_elems * sizeof(float), stream);

    detect_k<<<1, 256, 0, stream>>>(x, ei, flags);
    gemm1_k<<<N, 256, 0, stream>>>(x, W1, as1, ad1, h1, a_s1, a_d1, flags);
    denom1_k<<<(Etot + 255) / 256, 256, 0, stream>>>(ei, E, Etot, a_s1, a_d1, denom1, flags);
    scatter1_k<<<Etot, 256, 0, stream>>>(ei, E, Etot, a_s1, a_d1, denom1, h1, out1, flags);
    bias_elu1_k<<<(N * C1 + 255) / 256, 256, 0, stream>>>(out1, b1, N * C1, flags);
    gemm2_k<<<N, 64, 0, stream>>>(out1, W2, as2, ad2, h2, a_s2, a_d2, flags);
    denom2_k<<<(Etot + 255) / 256, 256, 0, stream>>>(ei, E, Etot, a_s2, a_d2, denom2, flags);
    scatter2_k<<<Etot, 64, 0, stream>>>(ei, E, Etot, a_s2, a_d2, denom2, h2, z0, flags);
    final_k<<<N, 64, 0, stream>>>(z0, b2, dW1, db1, dW2, db2, (float*)d_out, N, flags);
}

// Round 5
// 628.173 us; speedup vs baseline: 2.6925x; 2.6925x over previous
//
#include <hip/hip_runtime.h>
#include <hip/hip_bf16.h>

// GAT-GAE forward: 2x GATConv + normalize + MLP decoder. All fp32 I/O.
// Round 5: CSR-gather instead of atomic scatter (kills 1.1 GB of atomic
// traffic); fused denom+aggregate+bias+act per layer; 8-node-per-wave tiled
// GEMVs (8x less weight re-read). Softmax max-shift skipped (shift-invariant,
// logits O(6), exp clamped @60).
//
// Workspace (fp32 then int):
//   h1[N*256] | hx[N*256] | h2[N*64] | a_s1[N*4] | a_d1[N*4] | a_s2[N] |
//   a_d2[N] | rowptr[N+1] | cursor[N] | col[Etot]

#define IN_DIM   128
#define C1       256   // HEADS*HID
#define HEADS    4
#define HID      64
#define OUT_DIM  64

__device__ __forceinline__ float lrelu(float x) { return x > 0.f ? x : 0.2f * x; }
__device__ __forceinline__ float elu1(float x)  { return x > 0.f ? x : (__expf(x) - 1.f); }
__device__ __forceinline__ float expc(float x)  { return __expf(fminf(x, 60.f)); }

// ================= Layer-1 GEMV: h1 = x @ W1, logits =================
// block 256 = 4 waves; wave w handles 8 nodes; lane owns 4 channels.
__global__ __launch_bounds__(256) void gemm1_k(
    const float* __restrict__ x, const float* __restrict__ W1,
    const float* __restrict__ as1, const float* __restrict__ ad1,
    float* __restrict__ h1, float* __restrict__ a_s1, float* __restrict__ a_d1,
    int N)
{
    __shared__ float xs[32 * 128];   // per wave region w*1024, layout [k*8+nb]
    const int t  = threadIdx.x;
    const int n0 = blockIdx.x * 32;
    for (int i = t; i < 32 * 128; i += 256) {
        const int nb_l = i >> 7, k = i & 127;
        const int n = min(n0 + nb_l, N - 1);
        xs[(nb_l >> 3) * 1024 + k * 8 + (nb_l & 7)] = x[(size_t)n * IN_DIM + k];
    }
    __syncthreads();
    const int w = t >> 6, l = t & 63;
    const float* xw = xs + w * 1024;
    float4 acc[8];
    #pragma unroll
    for (int nb = 0; nb < 8; ++nb) acc[nb] = make_float4(0.f, 0.f, 0.f, 0.f);
    const float4* W1v = (const float4*)W1;   // W1[k*256 + l*4] = W1v[k*64 + l]
    #pragma unroll 4
    for (int k = 0; k < 128; ++k) {
        const float4 wa = W1v[k * 64 + l];
        const float4 xa = *(const float4*)&xw[k * 8];
        const float4 xb = *(const float4*)&xw[k * 8 + 4];
        const float xv[8] = {xa.x, xa.y, xa.z, xa.w, xb.x, xb.y, xb.z, xb.w};
        #pragma unroll
        for (int nb = 0; nb < 8; ++nb) {
            acc[nb].x += xv[nb] * wa.x;
            acc[nb].y += xv[nb] * wa.y;
            acc[nb].z += xv[nb] * wa.z;
            acc[nb].w += xv[nb] * wa.w;
        }
    }
    const float4 s4 = *(const float4*)&as1[l * 4];
    const float4 d4 = *(const float4*)&ad1[l * 4];
    #pragma unroll
    for (int nb = 0; nb < 8; ++nb) {
        const int n = n0 + w * 8 + nb;
        if (n >= N) break;
        *(float4*)&h1[(size_t)n * C1 + l * 4] = acc[nb];
        float vs = acc[nb].x * s4.x + acc[nb].y * s4.y + acc[nb].z * s4.z + acc[nb].w * s4.w;
        float vd = acc[nb].x * d4.x + acc[nb].y * d4.y + acc[nb].z * d4.z + acc[nb].w * d4.w;
        #pragma unroll
        for (int off = 1; off < 16; off <<= 1) {   // reduce within 16-lane head group
            vs += __shfl_xor(vs, off, 64);
            vd += __shfl_xor(vd, off, 64);
        }
        if ((l & 15) == 0) {
            a_s1[n * HEADS + (l >> 4)] = vs;
            a_d1[n * HEADS + (l >> 4)] = vd;
        }
    }
}

// ================= CSR build =================
__global__ void deg_k(const int* __restrict__ ei, int E, int Etot,
                      int* __restrict__ rowptr)
{
    const int e = blockIdx.x * blockDim.x + threadIdx.x;
    if (e >= Etot) return;
    const int d = (e < E) ? ei[E + e] : e - E;
    atomicAdd(&rowptr[1 + d], 1);
}

// single-block exclusive/inclusive scan; writes rowptr (inclusive at [1+i])
// and cursor[i] = exclusive prefix (segment start).
__global__ __launch_bounds__(1024) void scan_k(int* __restrict__ rowptr,
                                               int* __restrict__ cursor, int N)
{
    __shared__ int wsum[16];
    __shared__ int carry;
    const int t = threadIdx.x, lane = t & 63, wid = t >> 6;
    if (t == 0) carry = 0;
    __syncthreads();
    for (int base = 0; base < N; base += 1024) {
        const int i = base + t;
        const int v = (i < N) ? rowptr[1 + i] : 0;
        int sv = v;
        #pragma unroll
        for (int off = 1; off < 64; off <<= 1) {
            const int u = __shfl_up(sv, off, 64);
            if (lane >= off) sv += u;
        }
        if (lane == 63) wsum[wid] = sv;
        __syncthreads();
        if (wid == 0 && lane < 16) {
            int ws = wsum[lane];
            #pragma unroll
            for (int off = 1; off < 16; off <<= 1) {
                const int u = __shfl_up(ws, off, 16);
                if (lane >= off) ws += u;
            }
            wsum[lane] = ws;
        }
        __syncthreads();
        const int add = carry + (wid > 0 ? wsum[wid - 1] : 0);
        if (i < N) {
            rowptr[1 + i] = add + sv;
            cursor[i]     = add + sv - v;
        }
        __syncthreads();
        if (t == 0) carry += wsum[15];
        __syncthreads();
    }
}

__global__ void fill_k(const int* __restrict__ ei, int E, int Etot,
                       int* __restrict__ cursor, int* __restrict__ col)
{
    const int e = blockIdx.x * blockDim.x + threadIdx.x;
    if (e >= Etot) return;
    int s, d;
    if (e < E) { s = ei[e]; d = ei[E + e]; } else { s = d = e - E; }
    const int pos = atomicAdd(&cursor[d], 1);
    col[pos] = s;
}

// ================= Layer-1 aggregate (fused denom+msg+bias+ELU) =========
// block 256 per dst node; thread t = channel t, head t>>6; 2-deep pipeline.
__global__ __launch_bounds__(256) void agg1_k(
    const int* __restrict__ rowptr, const int* __restrict__ col,
    const float* __restrict__ a_s1, const float* __restrict__ a_d1,
    const float* __restrict__ h1, const float* __restrict__ b1,
    float* __restrict__ hout)
{
    const int d = blockIdx.x, t = threadIdx.x, head = t >> 6;
    const int beg = rowptr[d], end = rowptr[d + 1];
    const float ad = a_d1[d * HEADS + head];
    float acc = 0.f, wsum = 0.f;
    int   s  = col[beg];
    float as = a_s1[s * HEADS + head];
    float hv = h1[(size_t)s * C1 + t];
    for (int j = beg; j < end; ++j) {
        int s2 = 0; float as2 = 0.f, hv2 = 0.f;
        if (j + 1 < end) {
            s2  = col[j + 1];
            as2 = a_s1[s2 * HEADS + head];
            hv2 = h1[(size_t)s2 * C1 + t];
        }
        const float wgt = expc(lrelu(as + ad));
        acc  += hv * wgt;
        wsum += wgt;
        s = s2; as = as2; hv = hv2;
    }
    hout[(size_t)d * C1 + t] = elu1(acc / (wsum + 1e-16f) + b1[t]);
}

// ================= Layer-2 GEMV: h2 = h @ W2, logits =================
// block 256 = 4 waves; wave w -> 8 nodes; lane owns channel l.
__global__ __launch_bounds__(256) void gemm2_k(
    const float* __restrict__ h, const float* __restrict__ W2,
    const float* __restrict__ as2, const float* __restrict__ ad2,
    float* __restrict__ h2, float* __restrict__ a_s2, float* __restrict__ a_d2,
    int N)
{
    __shared__ float hs[32 * 256];   // 32 KB; wave region w*2048, [k*8+nb]
    const int t = threadIdx.x;
    const int n0 = blockIdx.x * 32;
    for (int i = t; i < 32 * 256; i += 256) {
        const int nb_l = i >> 8, k = i & 255;
        const int n = min(n0 + nb_l, N - 1);
        hs[(nb_l >> 3) * 2048 + k * 8 + (nb_l & 7)] = h[(size_t)n * C1 + k];
    }
    __syncthreads();
    const int w = t >> 6, l = t & 63;
    const float* hw = hs + w * 2048;
    float acc[8] = {0.f, 0.f, 0.f, 0.f, 0.f, 0.f, 0.f, 0.f};
    #pragma unroll 4
    for (int k = 0; k < 256; ++k) {
        const float wv = W2[k * OUT_DIM + l];
        const float4 xa = *(const float4*)&hw[k * 8];
        const float4 xb = *(const float4*)&hw[k * 8 + 4];
        acc[0] += xa.x * wv; acc[1] += xa.y * wv;
        acc[2] += xa.z * wv; acc[3] += xa.w * wv;
        acc[4] += xb.x * wv; acc[5] += xb.y * wv;
        acc[6] += xb.z * wv; acc[7] += xb.w * wv;
    }
    const float sv2 = as2[l], dv2 = ad2[l];
    #pragma unroll
    for (int nb = 0; nb < 8; ++nb) {
        const int n = n0 + w * 8 + nb;
        if (n >= N) break;
        h2[(size_t)n * OUT_DIM + l] = acc[nb];
        float vs = acc[nb] * sv2, vd = acc[nb] * dv2;
        #pragma unroll
        for (int off = 1; off < 64; off <<= 1) {
            vs += __shfl_xor(vs, off, 64);
            vd += __shfl_xor(vd, off, 64);
        }
        if (l == 0) { a_s2[n] = vs; a_d2[n] = vd; }
    }
}

// ========== Layer-2 aggregate + bias + L2-normalize -> z (in d_out) ==========
// block 64 per dst node.
__global__ __launch_bounds__(64) void agg2_k(
    const int* __restrict__ rowptr, const int* __restrict__ col,
    const float* __restrict__ a_s2, const float* __restrict__ a_d2,
    const float* __restrict__ h2, const float* __restrict__ b2,
    float* __restrict__ zout)
{
    const int d = blockIdx.x, t = threadIdx.x;
    const int beg = rowptr[d], end = rowptr[d + 1];
    const float ad = a_d2[d];
    float acc = 0.f, wsum = 0.f;
    int   s  = col[beg];
    float as = a_s2[s];
    float hv = h2[(size_t)s * OUT_DIM + t];
    for (int j = beg; j < end; ++j) {
        int s2 = 0; float as2 = 0.f, hv2 = 0.f;
        if (j + 1 < end) {
            s2  = col[j + 1];
            as2 = a_s2[s2];
            hv2 = h2[(size_t)s2 * OUT_DIM + t];
        }
        const float wgt = expc(lrelu(as + ad));
        acc  += hv * wgt;
        wsum += wgt;
        s = s2; as = as2; hv = hv2;
    }
    float z = acc / (wsum + 1e-16f) + b2[t];
    float sq = z * z;
    #pragma unroll
    for (int off = 1; off < 64; off <<= 1) sq += __shfl_xor(sq, off, 64);
    z /= fmaxf(sqrtf(sq), 1e-12f);
    zout[(size_t)d * OUT_DIM + t] = z;
}

// ================= Decoder: x_hat = elu(z@dW1+db1)@dW2+db2 =================
// block 256 = 4 waves; wave -> 8 nodes; z read from d_out.
__global__ __launch_bounds__(256) void dec_k(
    const float* __restrict__ z,
    const float* __restrict__ dW1, const float* __restrict__ db1,
    const float* __restrict__ dW2, const float* __restrict__ db2,
    float* __restrict__ xhat, int N)
{
    __shared__ float zs[32 * 64];   // wave region w*512, [k*8+nb]
    __shared__ float ts[32 * 64];   // same layout, k = hidden idx
    const int t = threadIdx.x;
    const int n0 = blockIdx.x * 32;
    for (int i = t; i < 32 * 64; i += 256) {
        const int nb_l = i >> 6, k = i & 63;
        const int n = min(n0 + nb_l, N - 1);
        zs[(nb_l >> 3) * 512 + k * 8 + (nb_l & 7)] = z[(size_t)n * OUT_DIM + k];
    }
    __syncthreads();
    const int w = t >> 6, l = t & 63;
    const float* zw = zs + w * 512;
    float* tw = ts + w * 512;
    float acc[8] = {0.f, 0.f, 0.f, 0.f, 0.f, 0.f, 0.f, 0.f};
    #pragma unroll 4
    for (int k = 0; k < 64; ++k) {
        const float wv = dW1[k * HID + l];
        const float4 xa = *(const float4*)&zw[k * 8];
        const float4 xb = *(const float4*)&zw[k * 8 + 4];
        acc[0] += xa.x * wv; acc[1] += xa.y * wv;
        acc[2] += xa.z * wv; acc[3] += xa.w * wv;
        acc[4] += xb.x * wv; acc[5] += xb.y * wv;
        acc[6] += xb.z * wv; acc[7] += xb.w * wv;
    }
    const float bb = db1[l];
    #pragma unroll
    for (int nb = 0; nb < 8; ++nb) tw[l * 8 + nb] = elu1(acc[nb] + bb);
    __syncthreads();
    float a0[8] = {0.f, 0.f, 0.f, 0.f, 0.f, 0.f, 0.f, 0.f};
    float a1[8] = {0.f, 0.f, 0.f, 0.f, 0.f, 0.f, 0.f, 0.f};
    #pragma unroll 2
    for (int k = 0; k < 64; ++k) {
        const float w0 = dW2[k * IN_DIM + l];
        const float w1 = dW2[k * IN_DIM + 64 + l];
        const float4 xa = *(const float4*)&tw[k * 8];
        const float4 xb = *(const float4*)&tw[k * 8 + 4];
        const float xv[8] = {xa.x, xa.y, xa.z, xa.w, xb.x, xb.y, xb.z, xb.w};
        #pragma unroll
        for (int nb = 0; nb < 8; ++nb) {
            a0[nb] += xv[nb] * w0;
            a1[nb] += xv[nb] * w1;
        }
    }
    const float bb0 = db2[l], bb1 = db2[64 + l];
    #pragma unroll
    for (int nb = 0; nb < 8; ++nb) {
        const int n = n0 + w * 8 + nb;
        if (n >= N) break;
        xhat[(size_t)n * IN_DIM + l]      = a0[nb] + bb0;
        xhat[(size_t)n * IN_DIM + 64 + l] = a1[nb] + bb1;
    }
}

extern "C" void kernel_launch(void* const* d_in, const int* in_sizes, int n_in,
                              void* d_out, int out_size, void* d_ws, size_t ws_size,
                              hipStream_t stream)
{
    const float* x   = (const float*)d_in[0];
    const int*   ei  = (const int*)d_in[1];
    const float* W1  = (const float*)d_in[2];
    const float* as1 = (const float*)d_in[3];
    const float* ad1 = (const float*)d_in[4];
    const float* b1  = (const float*)d_in[5];
    const float* W2  = (const float*)d_in[6];
    const float* as2 = (const float*)d_in[7];
    const float* ad2 = (const float*)d_in[8];
    const float* b2  = (const float*)d_in[9];
    const float* dW1 = (const float*)d_in[10];
    const float* db1 = (const float*)d_in[11];
    const float* dW2 = (const float*)d_in[12];
    const float* db2 = (const float*)d_in[13];

    const int N    = in_sizes[0] / IN_DIM;
    const int E    = in_sizes[1] / 2;
    const int Etot = E + N;

    float* ws = (float*)d_ws;
    float* h1   = ws;                          // N*256
    float* hx   = h1   + (size_t)N * C1;       // N*256
    float* h2   = hx   + (size_t)N * C1;       // N*64
    float* a_s1 = h2   + (size_t)N * OUT_DIM;  // N*4
    float* a_d1 = a_s1 + (size_t)N * HEADS;    // N*4
    float* a_s2 = a_d1 + (size_t)N * HEADS;    // N
    float* a_d2 = a_s2 + (size_t)N;            // N
    int* rowptr = (int*)(a_d2 + (size_t)N);    // N+1
    int* cursor = rowptr + (N + 1);            // N
    int* col    = cursor + N;                  // Etot

    const size_t needed = ((size_t)N * 586 + (size_t)2 * N + 1 + (size_t)Etot)
                          * sizeof(float);
    if (ws_size < needed) return;  // loud failure signature (absmax ~0.543)

    hipMemsetAsync(rowptr, 0, (size_t)(N + 1) * sizeof(int), stream);

    const int nblk = (N + 31) / 32;
    gemm1_k<<<nblk, 256, 0, stream>>>(x, W1, as1, ad1, h1, a_s1, a_d1, N);
    deg_k  <<<(Etot + 255) / 256, 256, 0, stream>>>(ei, E, Etot, rowptr);
    scan_k <<<1, 1024, 0, stream>>>(rowptr, cursor, N);
    fill_k <<<(Etot + 255) / 256, 256, 0, stream>>>(ei, E, Etot, cursor, col);
    agg1_k <<<N, 256, 0, stream>>>(rowptr, col, a_s1, a_d1, h1, b1, hx);
    gemm2_k<<<nblk, 256, 0, stream>>>(hx, W2, as2, ad2, h2, a_s2, a_d2, N);
    agg2_k <<<N, 64, 0, stream>>>(rowptr, col, a_s2, a_d2, h2, b2, (float*)d_out);
    dec_k  <<<nblk, 256, 0, stream>>>((const float*)d_out, dW1, db1, dW2, db2,
                                      (float*)d_out + (size_t)N * OUT_DIM, N);
}